// Round 11
// baseline (151.514 us; speedup 1.0000x reference)
//
#include <hip/hip_runtime.h>

#define Bb 8
#define Cc 256
#define C4 64
#define Nn 4096

typedef _Float16 half8 __attribute__((ext_vector_type(8)));
typedef float f32x4 __attribute__((ext_vector_type(4)));
typedef unsigned int u32;

__device__ __forceinline__ f32x4 fz4() {
  f32x4 z; z[0] = 0.f; z[1] = 0.f; z[2] = 0.f; z[3] = 0.f; return z;
}
__device__ __forceinline__ f32x4 mfma16(half8 a, half8 b, f32x4 c) {
  return __builtin_amdgcn_mfma_f32_16x16x32_f16(a, b, c, 0, 0, 0);
}
__device__ __forceinline__ u32 pkrtz(float a, float b) {
  typedef __fp16 h2n __attribute__((ext_vector_type(2)));
  h2n h = __builtin_amdgcn_cvt_pkrtz(a, b);
  return __builtin_bit_cast(u32, h);
}
__device__ __forceinline__ float ex2(float x) {
  float r;
  asm("v_exp_f32 %0, %1" : "=v"(r) : "v"(x));
  return r;
}

// Fragment-tiled f16 layout: tile = 16 rows x 32 k = 1KB, internally [(k>>3)&3][row&15][k&7].
// A/B-operand frag load = 64 lanes x 16B contiguous (byte = lane*16).

// ---------------- K0: weight prep -> fragment-tiled f16 (w_qk hi/lo, log2-scaled) ------
__global__ void k0_weights(const float* __restrict__ wqk, const float* __restrict__ wv,
                           const float* __restrict__ wt,
                           _Float16* __restrict__ wqkh, _Float16* __restrict__ wqkl,
                           _Float16* __restrict__ wvf, _Float16* __restrict__ wtf) {
  int idx = blockIdx.x * 256 + threadIdx.x;
  if (idx < C4 * Cc) {
    int o = idx >> 8, c = idx & 255;
    float f = wqk[idx] * 1.2011224087864498f;  // 1/sqrt(ln2): E' = E/ln2
    _Float16 h = (_Float16)f;
    int off = ((((o >> 4) * 8 + (c >> 5)) * 4 + ((c >> 3) & 3)) * 16 + (o & 15)) * 8 + (c & 7);
    wqkh[off] = h;
    wqkl[off] = (_Float16)(f - (float)h);
  }
  if (idx < Cc * Cc) {
    int o = idx >> 8, k = idx & 255;
    int off = ((((o >> 4) * 8 + (k >> 5)) * 4 + ((k >> 3) & 3)) * 16 + (o & 15)) * 8 + (k & 7);
    wvf[off] = (_Float16)wv[idx];
    wtf[off] = (_Float16)wt[idx];
  }
}

// ---------------- K23: qk + x_v, outputs fragment-tiled ----------------
__global__ __launch_bounds__(512) void k23_qkv(
    const float* __restrict__ x,
    const _Float16* __restrict__ wqkh, const _Float16* __restrict__ wqkl,
    const _Float16* __restrict__ wvf, const float* __restrict__ bv,
    _Float16* __restrict__ qkf, _Float16* __restrict__ xvf) {
  __shared__ _Float16 xh[64 * 264];  // [n][c] transposed x
  const int bid = blockIdx.x;
  const int b = bid & 7, n0 = (bid >> 3) * 64, tid = threadIdx.x;
  {
    const int cc = tid >> 3, nn = (tid & 7) * 8;
    #pragma unroll
    for (int ph = 0; ph < 4; ++ph) {
      int c = cc + ph * 64;
      const float* src = x + ((size_t)(b * Cc + c)) * Nn + n0 + nn;
      float4 v0 = *(const float4*)(src);
      float4 v1 = *(const float4*)(src + 4);
      float vv[8] = {v0.x, v0.y, v0.z, v0.w, v1.x, v1.y, v1.z, v1.w};
      #pragma unroll
      for (int j = 0; j < 8; ++j) xh[(nn + j) * 264 + c] = (_Float16)vv[j];
    }
  }
  __syncthreads();
  const int w = tid >> 6, lane = tid & 63, l15 = lane & 15, l4 = lane >> 4;
  {
    const int fn = w >> 1, ob = (w & 1) * 32;
    f32x4 acc[2] = {fz4(), fz4()};
    #pragma unroll
    for (int kb = 0; kb < 8; ++kb) {
      half8 ah = *(const half8*)(xh + (fn * 16 + l15) * 264 + kb * 32 + l4 * 8);
      #pragma unroll
      for (int f = 0; f < 2; ++f) {
        const int ot = (ob >> 4) + f;
        half8 bh = *(const half8*)((const char*)wqkh + (ot * 8 + kb) * 1024 + lane * 16);
        half8 bl = *(const half8*)((const char*)wqkl + (ot * 8 + kb) * 1024 + lane * 16);
        acc[f] = mfma16(ah, bh, acc[f]);
        acc[f] = mfma16(ah, bl, acc[f]);
      }
    }
    #pragma unroll
    for (int f = 0; f < 2; ++f)
      #pragma unroll
      for (int i = 0; i < 4; ++i) {
        const int n = n0 + fn * 16 + l4 * 4 + i;
        const int o = ob + f * 16 + l15;
        int off = ((((b * 256 + (n >> 4)) * 2 + (o >> 5)) * 4 + ((o >> 3) & 3)) * 16 +
                   (n & 15)) * 8 + (o & 7);
        qkf[off] = (_Float16)acc[f][i];
      }
  }
  {
    const int cb = w * 32;
    f32x4 acc[2][4];
    #pragma unroll
    for (int a = 0; a < 2; ++a)
      #pragma unroll
      for (int q = 0; q < 4; ++q) acc[a][q] = fz4();
    #pragma unroll
    for (int kb = 0; kb < 8; ++kb) {
      half8 bfr[4];
      #pragma unroll
      for (int fnb = 0; fnb < 4; ++fnb)
        bfr[fnb] = *(const half8*)(xh + (fnb * 16 + l15) * 264 + kb * 32 + l4 * 8);
      #pragma unroll
      for (int fc = 0; fc < 2; ++fc) {
        const int ct = (cb >> 4) + fc;
        half8 a = *(const half8*)((const char*)wvf + (ct * 8 + kb) * 1024 + lane * 16);
        #pragma unroll
        for (int fnb = 0; fnb < 4; ++fnb)
          acc[fc][fnb] = mfma16(a, bfr[fnb], acc[fc][fnb]);
      }
    }
    #pragma unroll
    for (int fc = 0; fc < 2; ++fc)
      #pragma unroll
      for (int fnb = 0; fnb < 4; ++fnb)
        #pragma unroll
        for (int i = 0; i < 4; ++i) {
          const int c = cb + fc * 16 + l4 * 4 + i;
          const int n = n0 + fnb * 16 + l15;
          int off = ((((b * 16 + (c >> 4)) * 128 + (n >> 5)) * 4 + ((n >> 3) & 3)) * 16 +
                     (c & 15)) * 8 + (n & 7);
          xvf[off] = (_Float16)(acc[fc][fnb][i] + bv[c]);
        }
  }
}

// ---------------- K4: softmax row stats  a'_n = 32 + log2(sum 2^(E'-32)) ----------------
__global__ __launch_bounds__(512, 4) void k4_stats(
    const _Float16* __restrict__ qkf, float* __restrict__ stats) {
  __shared__ float red[64][8];
  const int bid = blockIdx.x;
  const int b = bid & 7, n0 = (bid >> 3) * 64, tid = threadIdx.x;
  const int w = tid >> 6, lane = tid & 63, l15 = lane & 15, l4 = lane >> 4;
  const char* qbt = (const char*)qkf + (size_t)b * 524288;

  half8 qn_r[2][4];
  #pragma unroll
  for (int kb = 0; kb < 2; ++kb)
    #pragma unroll
    for (int fn = 0; fn < 4; ++fn)
      qn_r[kb][fn] = *(const half8*)(qbt + (((n0 >> 4) + fn) * 2 + kb) * 1024 + lane * 16);

  const char* qp = qbt + w * 2048 + lane * 16;
  half8 qa0 = *(const half8*)qp;
  half8 qa1 = *(const half8*)(qp + 1024);

  float sm[4] = {0.f, 0.f, 0.f, 0.f};
  for (int it = 0; it < 32; ++it) {
    f32x4 g[4] = {fz4(), fz4(), fz4(), fz4()};
    #pragma unroll
    for (int fn = 0; fn < 4; ++fn) g[fn] = mfma16(qa0, qn_r[0][fn], g[fn]);
    #pragma unroll
    for (int fn = 0; fn < 4; ++fn) g[fn] = mfma16(qa1, qn_r[1][fn], g[fn]);
    if (it < 31) qp += 16384;
    qa0 = *(const half8*)qp;
    qa1 = *(const half8*)(qp + 1024);
    #pragma unroll
    for (int fn = 0; fn < 4; ++fn)
      #pragma unroll
      for (int i = 0; i < 4; ++i)
        sm[fn] += ex2(g[fn][i] - 32.0f);
  }
  #pragma unroll
  for (int fn = 0; fn < 4; ++fn) {
    sm[fn] += __shfl_xor(sm[fn], 16, 64);
    sm[fn] += __shfl_xor(sm[fn], 32, 64);
  }
  if (l4 == 0) {
    #pragma unroll
    for (int fn = 0; fn < 4; ++fn) red[fn * 16 + l15][w] = sm[fn];
  }
  __syncthreads();
  if (tid < 64) {
    float t = 0.f;
    #pragma unroll
    for (int j = 0; j < 8; ++j) t += red[tid][j];
    stats[(size_t)b * Nn + n0 + tid] = 32.0f + log2f(t);
  }
}

// ---------------- K5: m128 x c256 tile; anti-phased wave groups ----------------
// Waves wa=0: {loads, G[it], exp, PTw[it], PV[it-1]} ; wa=1: {PV[it-1], loads, G, exp, PTw}.
// One A and one B wave per SIMD -> G/exp VALU of one hides under PV MFMA of the other.
__global__ __launch_bounds__(512, 2) void k5_main(
    const float* __restrict__ x,
    const _Float16* __restrict__ qkf, const _Float16* __restrict__ xvf,
    const float* __restrict__ stats,
    const _Float16* __restrict__ wtf, const float* __restrict__ bt,
    const float* __restrict__ gamma, const float* __restrict__ beta,
    const float* __restrict__ rmean, const float* __restrict__ rvar,
    float* __restrict__ out) {
  // loop: an [0,16K) | PT0 [16K,32K) | PT1 [32K,48K).  epilogue: st[128][264] f16
  __shared__ __align__(16) char smem[69632];
  const int bid = blockIdx.x;
  const int b = bid & 7, m0 = (bid >> 3) * 128, tid = threadIdx.x;
  const int w = tid >> 6, lane = tid & 63, l15 = lane & 15, l4 = lane >> 4;
  const int wa = w >> 2;  // m 64-half; also the phase group
  const int wb = w & 3;   // G: n16 quarter; PV: c64 quarter
  const size_t bq = (size_t)b * Nn;
  const char* qkt = (const char*)qkf + (size_t)b * 524288;
  const char* xvt = (const char*)xvf + (size_t)b * 2097152;
  const int key = l15 & 7;
  float* anL = (float*)smem;

  // stationary qm: B-operand frags for wave's m64 (4 m-tiles x 2 kb)
  half8 qm_r[2][4];
  #pragma unroll
  for (int kb = 0; kb < 2; ++kb)
    #pragma unroll
    for (int fm = 0; fm < 4; ++fm)
      qm_r[kb][fm] = *(const half8*)(qkt + ((((m0 >> 4) + wa * 4 + fm) * 2) + kb) * 1024 +
                                     lane * 16);

  const char* ah_base = qkt + (wb * 2) * 1024 + (size_t)lane * 16;            // +8192/it
  const char* xb_base = xvt + (size_t)(wb * 4) * 131072 + (size_t)lane * 16;  // +2048/it

  f32x4 acc[4][4];
  #pragma unroll
  for (int a = 0; a < 4; ++a)
    #pragma unroll
    for (int q = 0; q < 4; ++q) acc[a][q] = fz4();

  // prologue: stage an (whole batch, 16KB); load ah[0] (parity 0)
  #pragma unroll
  for (int j = 0; j < 2; ++j)
    ((float4*)anL)[tid + 512 * j] = ((const float4*)(stats + bq))[tid + 512 * j];
  half8 ahA[2] = {}, ahB[2] = {}, xbA[4][2] = {}, xbB[4][2] = {};
  #pragma unroll
  for (int kb = 0; kb < 2; ++kb) ahA[kb] = *(const half8*)(ah_base + kb * 1024);
  __syncthreads();

#define K5_PV(PTR_, XB_)                                                            \
  {                                                                                \
    __builtin_amdgcn_s_setprio(1);                                                 \
    _Pragma("unroll") for (int kb = 0; kb < 2; ++kb) {                             \
      half8 pa[4];                                                                 \
      _Pragma("unroll") for (int fm = 0; fm < 4; ++fm)                             \
          pa[fm] = *(const half8*)((PTR_) + (wa * 64 + fm * 16 + l15) * 128 +      \
                                   (((kb * 4 + l4) ^ key) * 16));                  \
      _Pragma("unroll") for (int fm = 0; fm < 4; ++fm)                             \
        _Pragma("unroll") for (int fc = 0; fc < 4; ++fc)                           \
            acc[fm][fc] = mfma16(pa[fm], (XB_)[fc][kb], acc[fm][fc]);              \
    }                                                                              \
    __builtin_amdgcn_s_setprio(0);                                                 \
  }

#define K5_STEP(P, FIRST, AH_CUR, AH_NXT, XB_THIS, XB_PREV)                         \
  {                                                                                \
    const int it = it2 * 2 + (P);                                                  \
    float4 an = *(const float4*)(anL + it * 64 + wb * 16 + l4 * 4);                \
    {                                                                              \
      const char* ahs = ah_base + (size_t)(it + 1) * 8192;                         \
      _Pragma("unroll") for (int kb = 0; kb < 2; ++kb)                             \
          AH_NXT[kb] = *(const half8*)(ahs + kb * 1024);                           \
      const char* xbs = xb_base + (size_t)it * 2048;                               \
      _Pragma("unroll") for (int fc = 0; fc < 4; ++fc)                             \
        _Pragma("unroll") for (int kb = 0; kb < 2; ++kb)                           \
            XB_THIS[fc][kb] = *(const half8*)(xbs + fc * 131072 + kb * 1024);      \
    }                                                                              \
    char* PTw = smem + 16384 + ((P) << 14);                                        \
    char* PTr = smem + 16384 + (((P) ^ 1) << 14);                                  \
    if (!(FIRST) && wa == 1) K5_PV(PTr, XB_PREV);                                  \
    f32x4 g[4] = {fz4(), fz4(), fz4(), fz4()};                                     \
    _Pragma("unroll") for (int kb = 0; kb < 2; ++kb)                               \
      _Pragma("unroll") for (int fm = 0; fm < 4; ++fm)                             \
          g[fm] = mfma16(AH_CUR[kb], qm_r[kb][fm], g[fm]);                         \
    _Pragma("unroll") for (int fm = 0; fm < 4; ++fm) {                             \
      uint2 pk;                                                                    \
      pk.x = pkrtz(ex2(g[fm][0] - an.x), ex2(g[fm][1] - an.y));                    \
      pk.y = pkrtz(ex2(g[fm][2] - an.z), ex2(g[fm][3] - an.w));                    \
      *(uint2*)(PTw + (wa * 64 + fm * 16 + l15) * 128 +                            \
                ((wb * 32 + l4 * 8) ^ (key << 4))) = pk;                           \
    }                                                                              \
    if (!(FIRST) && wa == 0) K5_PV(PTr, XB_PREV);                                  \
    asm volatile("s_waitcnt lgkmcnt(0)" ::: "memory");                             \
    __builtin_amdgcn_sched_barrier(0);                                             \
    __builtin_amdgcn_s_barrier();                                                  \
  }

  {
    const int it2 = 0;
    K5_STEP(0, 1, ahA, ahB, xbA, xbB)
    K5_STEP(1, 0, ahB, ahA, xbB, xbA)
  }
  for (int it2 = 1; it2 < 32; ++it2) {
    K5_STEP(0, 0, ahA, ahB, xbA, xbB)
    K5_STEP(1, 0, ahB, ahA, xbB, xbA)
  }
  // final PV[63]: PT buf 1, xb parity 1
  {
    char* PTr = smem + 16384 + 16384;
    K5_PV(PTr, xbB);
  }
#undef K5_STEP
#undef K5_PV
  asm volatile("s_waitcnt lgkmcnt(0)" ::: "memory");
  __builtin_amdgcn_sched_barrier(0);
  __builtin_amdgcn_s_barrier();

  // ---- Epilogue: s^T = x - x_r^T into st[128][264] f16 ----
  _Float16* st = (_Float16*)smem;
  #pragma unroll
  for (int fm = 0; fm < 4; ++fm)
    #pragma unroll
    for (int fc = 0; fc < 4; ++fc) {
      int c = wb * 64 + fc * 16 + l15;
      int mb = wa * 64 + fm * 16 + l4 * 4;
      const float* xp = x + ((size_t)b * Cc + c) * Nn + m0 + mb;
      float4 v = *(const float4*)xp;
      float vv[4] = {v.x, v.y, v.z, v.w};
      #pragma unroll
      for (int i = 0; i < 4; ++i)
        st[(mb + i) * 264 + c] = (_Float16)(vv[i] - acc[fm][fc][i]);
    }
  __syncthreads();
  // ---- t = w_t . s + b_t, BN, ReLU, +x ; wave = o64(wb) x m64(wa) ----
  {
    const int ob = wb * 64, mh = wa * 64;
    f32x4 t[4][4];
    #pragma unroll
    for (int a = 0; a < 4; ++a)
      #pragma unroll
      for (int q = 0; q < 4; ++q) t[a][q] = fz4();
    #pragma unroll
    for (int kb = 0; kb < 8; ++kb) {
      half8 bfr[4];
      #pragma unroll
      for (int fm2 = 0; fm2 < 4; ++fm2)
        bfr[fm2] = *(const half8*)(st + (mh + fm2 * 16 + l15) * 264 + kb * 32 + l4 * 8);
      #pragma unroll
      for (int fo = 0; fo < 4; ++fo) {
        const int ot = (ob >> 4) + fo;
        half8 a = *(const half8*)((const char*)wtf + (ot * 8 + kb) * 1024 + lane * 16);
        #pragma unroll
        for (int fm2 = 0; fm2 < 4; ++fm2)
          t[fo][fm2] = mfma16(a, bfr[fm2], t[fo][fm2]);
      }
    }
    #pragma unroll
    for (int fo = 0; fo < 4; ++fo)
      #pragma unroll
      for (int i = 0; i < 4; ++i) {
        const int o = ob + fo * 16 + l4 * 4 + i;
        const float inv = gamma[o] * rsqrtf(rvar[o] + 1e-5f);
        const float addv = beta[o] - rmean[o] * inv;
        const float btv = bt[o];
        #pragma unroll
        for (int fm2 = 0; fm2 < 4; ++fm2) {
          const int m = m0 + mh + fm2 * 16 + l15;
          float tv = t[fo][fm2][i] + btv;
          float bn = tv * inv + addv;
          float xr = x[((size_t)b * Cc + o) * Nn + m];
          out[((size_t)b * Cc + o) * Nn + m] = xr + fmaxf(bn, 0.0f);
        }
      }
  }
}

extern "C" void kernel_launch(void* const* d_in, const int* in_sizes, int n_in,
                              void* d_out, int out_size, void* d_ws, size_t ws_size,
                              hipStream_t stream) {
  const float* x = (const float*)d_in[0];
  const float* wqk = (const float*)d_in[1];
  const float* wv = (const float*)d_in[2];
  const float* bv = (const float*)d_in[3];
  const float* wt = (const float*)d_in[4];
  const float* bt = (const float*)d_in[5];
  const float* gamma = (const float*)d_in[6];
  const float* beta = (const float*)d_in[7];
  const float* rmean = (const float*)d_in[8];
  const float* rvar = (const float*)d_in[9];
  float* out = (float*)d_out;

  char* ws = (char*)d_ws;
  size_t off = 0;
  auto alloc = [&](size_t nb) {
    char* p = ws + off;
    off += (nb + 255) & ~(size_t)255;
    return p;
  };
  _Float16* qkf = (_Float16*)alloc((size_t)Bb * Nn * C4 * 2);
  _Float16* xvf = (_Float16*)alloc((size_t)Bb * Cc * Nn * 2);
  float* stats = (float*)alloc((size_t)Bb * Nn * 4);
  _Float16* wqkh = (_Float16*)alloc((size_t)C4 * Cc * 2);
  _Float16* wqkl = (_Float16*)alloc((size_t)C4 * Cc * 2);
  _Float16* wvf = (_Float16*)alloc((size_t)Cc * Cc * 2);
  _Float16* wtf = (_Float16*)alloc((size_t)Cc * Cc * 2);

  k0_weights<<<dim3(256), dim3(256), 0, stream>>>(wqk, wv, wt, wqkh, wqkl, wvf, wtf);
  k23_qkv<<<dim3(512), dim3(512), 0, stream>>>(x, wqkh, wqkl, wvf, bv, qkf, xvf);
  k4_stats<<<dim3(512), dim3(512), 0, stream>>>(qkf, stats);
  k5_main<<<dim3(256), dim3(512), 0, stream>>>(x, qkf, xvf, stats, wtf, bt,
                                               gamma, beta, rmean, rvar, out);
}

// Round 12
// 133.464 us; speedup vs baseline: 1.1352x; 1.1352x over previous
//
#include <hip/hip_runtime.h>

#define Bb 8
#define Cc 256
#define C4 64
#define Nn 4096

typedef _Float16 half8 __attribute__((ext_vector_type(8)));
typedef float f32x4 __attribute__((ext_vector_type(4)));
typedef unsigned int u32;

__device__ __forceinline__ f32x4 fz4() {
  f32x4 z; z[0] = 0.f; z[1] = 0.f; z[2] = 0.f; z[3] = 0.f; return z;
}
__device__ __forceinline__ f32x4 mfma16(half8 a, half8 b, f32x4 c) {
  return __builtin_amdgcn_mfma_f32_16x16x32_f16(a, b, c, 0, 0, 0);
}
__device__ __forceinline__ u32 pkrtz(float a, float b) {
  typedef __fp16 h2n __attribute__((ext_vector_type(2)));
  h2n h = __builtin_amdgcn_cvt_pkrtz(a, b);
  return __builtin_bit_cast(u32, h);
}
__device__ __forceinline__ float ex2(float x) {
  float r;
  asm("v_exp_f32 %0, %1" : "=v"(r) : "v"(x));
  return r;
}

// Fragment-tiled f16 layout: tile = 16 rows x 32 k = 1KB, internally [(k>>3)&3][row&15][k&7].
// A/B-operand frag load = 64 lanes x 16B contiguous (byte = lane*16).

// ---------------- K0: weight prep -> fragment-tiled f16 (w_qk hi/lo, log2-scaled) ------
__global__ void k0_weights(const float* __restrict__ wqk, const float* __restrict__ wv,
                           const float* __restrict__ wt,
                           _Float16* __restrict__ wqkh, _Float16* __restrict__ wqkl,
                           _Float16* __restrict__ wvf, _Float16* __restrict__ wtf) {
  int idx = blockIdx.x * 256 + threadIdx.x;
  if (idx < C4 * Cc) {
    int o = idx >> 8, c = idx & 255;
    float f = wqk[idx] * 1.2011224087864498f;  // 1/sqrt(ln2): E' = E/ln2
    _Float16 h = (_Float16)f;
    int off = ((((o >> 4) * 8 + (c >> 5)) * 4 + ((c >> 3) & 3)) * 16 + (o & 15)) * 8 + (c & 7);
    wqkh[off] = h;
    wqkl[off] = (_Float16)(f - (float)h);
  }
  if (idx < Cc * Cc) {
    int o = idx >> 8, k = idx & 255;
    int off = ((((o >> 4) * 8 + (k >> 5)) * 4 + ((k >> 3) & 3)) * 16 + (o & 15)) * 8 + (k & 7);
    wvf[off] = (_Float16)wv[idx];
    wtf[off] = (_Float16)wt[idx];
  }
}

// ---------------- K23: qk + x_v, outputs fragment-tiled ----------------
__global__ __launch_bounds__(512) void k23_qkv(
    const float* __restrict__ x,
    const _Float16* __restrict__ wqkh, const _Float16* __restrict__ wqkl,
    const _Float16* __restrict__ wvf, const float* __restrict__ bv,
    _Float16* __restrict__ qkf, _Float16* __restrict__ xvf) {
  __shared__ _Float16 xh[64 * 264];  // [n][c] transposed x
  const int bid = blockIdx.x;
  const int b = bid & 7, n0 = (bid >> 3) * 64, tid = threadIdx.x;
  {
    const int cc = tid >> 3, nn = (tid & 7) * 8;
    #pragma unroll
    for (int ph = 0; ph < 4; ++ph) {
      int c = cc + ph * 64;
      const float* src = x + ((size_t)(b * Cc + c)) * Nn + n0 + nn;
      float4 v0 = *(const float4*)(src);
      float4 v1 = *(const float4*)(src + 4);
      float vv[8] = {v0.x, v0.y, v0.z, v0.w, v1.x, v1.y, v1.z, v1.w};
      #pragma unroll
      for (int j = 0; j < 8; ++j) xh[(nn + j) * 264 + c] = (_Float16)vv[j];
    }
  }
  __syncthreads();
  const int w = tid >> 6, lane = tid & 63, l15 = lane & 15, l4 = lane >> 4;
  {
    const int fn = w >> 1, ob = (w & 1) * 32;
    f32x4 acc[2] = {fz4(), fz4()};
    #pragma unroll
    for (int kb = 0; kb < 8; ++kb) {
      half8 ah = *(const half8*)(xh + (fn * 16 + l15) * 264 + kb * 32 + l4 * 8);
      #pragma unroll
      for (int f = 0; f < 2; ++f) {
        const int ot = (ob >> 4) + f;
        half8 bh = *(const half8*)((const char*)wqkh + (ot * 8 + kb) * 1024 + lane * 16);
        half8 bl = *(const half8*)((const char*)wqkl + (ot * 8 + kb) * 1024 + lane * 16);
        acc[f] = mfma16(ah, bh, acc[f]);
        acc[f] = mfma16(ah, bl, acc[f]);
      }
    }
    #pragma unroll
    for (int f = 0; f < 2; ++f)
      #pragma unroll
      for (int i = 0; i < 4; ++i) {
        const int n = n0 + fn * 16 + l4 * 4 + i;
        const int o = ob + f * 16 + l15;
        int off = ((((b * 256 + (n >> 4)) * 2 + (o >> 5)) * 4 + ((o >> 3) & 3)) * 16 +
                   (n & 15)) * 8 + (o & 7);
        qkf[off] = (_Float16)acc[f][i];
      }
  }
  {
    const int cb = w * 32;
    f32x4 acc[2][4];
    #pragma unroll
    for (int a = 0; a < 2; ++a)
      #pragma unroll
      for (int q = 0; q < 4; ++q) acc[a][q] = fz4();
    #pragma unroll
    for (int kb = 0; kb < 8; ++kb) {
      half8 bfr[4];
      #pragma unroll
      for (int fnb = 0; fnb < 4; ++fnb)
        bfr[fnb] = *(const half8*)(xh + (fnb * 16 + l15) * 264 + kb * 32 + l4 * 8);
      #pragma unroll
      for (int fc = 0; fc < 2; ++fc) {
        const int ct = (cb >> 4) + fc;
        half8 a = *(const half8*)((const char*)wvf + (ct * 8 + kb) * 1024 + lane * 16);
        #pragma unroll
        for (int fnb = 0; fnb < 4; ++fnb)
          acc[fc][fnb] = mfma16(a, bfr[fnb], acc[fc][fnb]);
      }
    }
    #pragma unroll
    for (int fc = 0; fc < 2; ++fc)
      #pragma unroll
      for (int fnb = 0; fnb < 4; ++fnb)
        #pragma unroll
        for (int i = 0; i < 4; ++i) {
          const int c = cb + fc * 16 + l4 * 4 + i;
          const int n = n0 + fnb * 16 + l15;
          int off = ((((b * 16 + (c >> 4)) * 128 + (n >> 5)) * 4 + ((n >> 3) & 3)) * 16 +
                     (c & 15)) * 8 + (n & 7);
          xvf[off] = (_Float16)(acc[fc][fnb][i] + bv[c]);
        }
  }
}

// ---------------- K4: softmax row stats  a'_n = 32 + log2(sum 2^(E'-32)) ----------------
__global__ __launch_bounds__(512, 4) void k4_stats(
    const _Float16* __restrict__ qkf, float* __restrict__ stats) {
  __shared__ float red[64][8];
  const int bid = blockIdx.x;
  const int b = bid & 7, n0 = (bid >> 3) * 64, tid = threadIdx.x;
  const int w = tid >> 6, lane = tid & 63, l15 = lane & 15, l4 = lane >> 4;
  const char* qbt = (const char*)qkf + (size_t)b * 524288;

  half8 qn_r[2][4];
  #pragma unroll
  for (int kb = 0; kb < 2; ++kb)
    #pragma unroll
    for (int fn = 0; fn < 4; ++fn)
      qn_r[kb][fn] = *(const half8*)(qbt + (((n0 >> 4) + fn) * 2 + kb) * 1024 + lane * 16);

  const char* qp = qbt + w * 2048 + lane * 16;
  half8 qa0 = *(const half8*)qp;
  half8 qa1 = *(const half8*)(qp + 1024);

  float sm[4] = {0.f, 0.f, 0.f, 0.f};
  for (int it = 0; it < 32; ++it) {
    f32x4 g[4] = {fz4(), fz4(), fz4(), fz4()};
    #pragma unroll
    for (int fn = 0; fn < 4; ++fn) g[fn] = mfma16(qa0, qn_r[0][fn], g[fn]);
    #pragma unroll
    for (int fn = 0; fn < 4; ++fn) g[fn] = mfma16(qa1, qn_r[1][fn], g[fn]);
    if (it < 31) qp += 16384;
    qa0 = *(const half8*)qp;
    qa1 = *(const half8*)(qp + 1024);
    #pragma unroll
    for (int fn = 0; fn < 4; ++fn)
      #pragma unroll
      for (int i = 0; i < 4; ++i)
        sm[fn] += ex2(g[fn][i] - 32.0f);
  }
  #pragma unroll
  for (int fn = 0; fn < 4; ++fn) {
    sm[fn] += __shfl_xor(sm[fn], 16, 64);
    sm[fn] += __shfl_xor(sm[fn], 32, 64);
  }
  if (l4 == 0) {
    #pragma unroll
    for (int fn = 0; fn < 4; ++fn) red[fn * 16 + l15][w] = sm[fn];
  }
  __syncthreads();
  if (tid < 64) {
    float t = 0.f;
    #pragma unroll
    for (int j = 0; j < 8; ++j) t += red[tid][j];
    stats[(size_t)b * Nn + n0 + tid] = 32.0f + log2f(t);
  }
}

// ---------------- K5: m64 x c256 blocks (256 thr, 4 waves), 2 independent blocks/CU ----
// Round-10 dataflow exactly; sync topology change only: 8-wave lockstep -> 2x4-wave
// free-running blocks, so one block's PV MFMAs cover the other's exp/barrier phase.
__global__ __launch_bounds__(256, 2) void k5_main(
    const float* __restrict__ x,
    const _Float16* __restrict__ qkf, const _Float16* __restrict__ xvf,
    const float* __restrict__ stats,
    const _Float16* __restrict__ wtf, const float* __restrict__ bt,
    const float* __restrict__ gamma, const float* __restrict__ beta,
    const float* __restrict__ rmean, const float* __restrict__ rvar,
    float* __restrict__ out) {
  // loop: an [0,16K) | PT0 [16K,24K) | PT1 [24K,32K).  epilogue: st[64][264] f16 (33.8K)
  __shared__ __align__(16) char smem[34048];
  const int bid = blockIdx.x;
  const int b = bid & 7, m0 = (bid >> 3) * 64, tid = threadIdx.x;
  const int w = tid >> 6, lane = tid & 63, l15 = lane & 15, l4 = lane >> 4;
  const int wb = w;  // G: n16 quarter; PV: c64 quarter
  const size_t bq = (size_t)b * Nn;
  const char* qkt = (const char*)qkf + (size_t)b * 524288;
  const char* xvt = (const char*)xvf + (size_t)b * 2097152;
  const int key = l15 & 7;
  float* anL = (float*)smem;

  // stationary qm: B-operand frags for block's m64 (4 m-tiles x 2 kb)
  half8 qm_r[2][4];
  #pragma unroll
  for (int kb = 0; kb < 2; ++kb)
    #pragma unroll
    for (int fm = 0; fm < 4; ++fm)
      qm_r[kb][fm] = *(const half8*)(qkt + ((((m0 >> 4) + fm) * 2) + kb) * 1024 + lane * 16);

  const char* ah_base = qkt + (wb * 2) * 1024 + (size_t)lane * 16;            // +8192/it
  const char* xb_base = xvt + (size_t)(wb * 4) * 131072 + (size_t)lane * 16;  // +2048/it

  f32x4 acc[4][4];
  #pragma unroll
  for (int a = 0; a < 4; ++a)
    #pragma unroll
    for (int q = 0; q < 4; ++q) acc[a][q] = fz4();

  // prologue: stage an (whole batch, 16KB), load ah[0]/xb[0] into A-buffers
  #pragma unroll
  for (int j = 0; j < 4; ++j)
    ((float4*)anL)[tid + 256 * j] = ((const float4*)(stats + bq))[tid + 256 * j];
  half8 ahA[2], ahB[2], xbA[4][2], xbB[4][2];
  #pragma unroll
  for (int kb = 0; kb < 2; ++kb) ahA[kb] = *(const half8*)(ah_base + kb * 1024);
  #pragma unroll
  for (int fc = 0; fc < 4; ++fc)
    #pragma unroll
    for (int kb = 0; kb < 2; ++kb)
      xbA[fc][kb] = *(const half8*)(xb_base + fc * 131072 + kb * 1024);
  __syncthreads();

#define K5_STEP(P, AH_CUR, AH_NXT, XB_CUR, XB_NXT)                                  \
  {                                                                                \
    const int it = it2 * 2 + (P);                                                  \
    /* issue next-iter operand loads (full-iteration latency cover) */             \
    {                                                                              \
      const char* ahs = ah_base + (size_t)(it + 1) * 8192;                         \
      _Pragma("unroll") for (int kb = 0; kb < 2; ++kb)                             \
          AH_NXT[kb] = *(const half8*)(ahs + kb * 1024);                           \
      const char* xbs = xb_base + (size_t)(it + 1) * 2048;                         \
      _Pragma("unroll") for (int fc = 0; fc < 4; ++fc)                             \
        _Pragma("unroll") for (int kb = 0; kb < 2; ++kb)                           \
            XB_NXT[fc][kb] = *(const half8*)(xbs + fc * 131072 + kb * 1024);       \
    }                                                                              \
    /* G: D[n16][m64] */                                                           \
    f32x4 g[4] = {fz4(), fz4(), fz4(), fz4()};                                     \
    _Pragma("unroll") for (int kb = 0; kb < 2; ++kb)                               \
      _Pragma("unroll") for (int fm = 0; fm < 4; ++fm)                             \
          g[fm] = mfma16(AH_CUR[kb], qm_r[kb][fm], g[fm]);                         \
    /* P = 2^(E' - a'_n) -> PT[m64][n64] swizzled */                               \
    char* PTp = smem + 16384 + ((P) << 13);                                        \
    {                                                                              \
      float4 an = *(const float4*)(anL + it * 64 + wb * 16 + l4 * 4);              \
      _Pragma("unroll") for (int fm = 0; fm < 4; ++fm) {                           \
        uint2 pk;                                                                  \
        pk.x = pkrtz(ex2(g[fm][0] - an.x), ex2(g[fm][1] - an.y));                  \
        pk.y = pkrtz(ex2(g[fm][2] - an.z), ex2(g[fm][3] - an.w));                  \
        *(uint2*)(PTp + (fm * 16 + l15) * 128 +                                    \
                  ((wb * 32 + l4 * 8) ^ (key << 4))) = pk;                         \
      }                                                                            \
    }                                                                              \
    /* barrier: PT handoff only */                                                 \
    asm volatile("s_waitcnt lgkmcnt(0)" ::: "memory");                             \
    __builtin_amdgcn_sched_barrier(0);                                             \
    __builtin_amdgcn_s_barrier();                                                  \
    /* PV: acc[m64][c64] += P[m][n] * xv[c][n] */                                  \
    __builtin_amdgcn_s_setprio(1);                                                 \
    _Pragma("unroll") for (int kb = 0; kb < 2; ++kb) {                             \
      half8 pa[4];                                                                 \
      _Pragma("unroll") for (int fm = 0; fm < 4; ++fm)                             \
          pa[fm] = *(const half8*)(PTp + (fm * 16 + l15) * 128 +                   \
                                   (((kb * 4 + l4) ^ key) * 16));                  \
      _Pragma("unroll") for (int fm = 0; fm < 4; ++fm)                             \
        _Pragma("unroll") for (int fc = 0; fc < 4; ++fc)                           \
            acc[fm][fc] = mfma16(pa[fm], XB_CUR[fc][kb], acc[fm][fc]);             \
    }                                                                              \
    __builtin_amdgcn_s_setprio(0);                                                 \
  }

  for (int it2 = 0; it2 < 32; ++it2) {
    K5_STEP(0, ahA, ahB, xbA, xbB)
    K5_STEP(1, ahB, ahA, xbB, xbA)
  }
#undef K5_STEP
  asm volatile("s_waitcnt lgkmcnt(0)" ::: "memory");
  __builtin_amdgcn_sched_barrier(0);
  __builtin_amdgcn_s_barrier();

  // ---- Epilogue: s^T = x - x_r^T into st[64][264] f16 ----
  _Float16* st = (_Float16*)smem;
  #pragma unroll
  for (int fm = 0; fm < 4; ++fm)
    #pragma unroll
    for (int fc = 0; fc < 4; ++fc) {
      int c = wb * 64 + fc * 16 + l15;
      int mb = fm * 16 + l4 * 4;
      const float* xp = x + ((size_t)b * Cc + c) * Nn + m0 + mb;
      float4 v = *(const float4*)xp;
      float vv[4] = {v.x, v.y, v.z, v.w};
      #pragma unroll
      for (int i = 0; i < 4; ++i)
        st[(mb + i) * 264 + c] = (_Float16)(vv[i] - acc[fm][fc][i]);
    }
  __syncthreads();
  // ---- t = w_t . s + b_t, BN, ReLU, +x ; wave = o64(w) x m64 ----
  {
    const int ob = w * 64;
    f32x4 t[4][4];
    #pragma unroll
    for (int a = 0; a < 4; ++a)
      #pragma unroll
      for (int q = 0; q < 4; ++q) t[a][q] = fz4();
    #pragma unroll
    for (int kb = 0; kb < 8; ++kb) {
      half8 bfr[4];
      #pragma unroll
      for (int fm2 = 0; fm2 < 4; ++fm2)
        bfr[fm2] = *(const half8*)(st + (fm2 * 16 + l15) * 264 + kb * 32 + l4 * 8);
      #pragma unroll
      for (int fo = 0; fo < 4; ++fo) {
        const int ot = (ob >> 4) + fo;
        half8 a = *(const half8*)((const char*)wtf + (ot * 8 + kb) * 1024 + lane * 16);
        #pragma unroll
        for (int fm2 = 0; fm2 < 4; ++fm2)
          t[fo][fm2] = mfma16(a, bfr[fm2], t[fo][fm2]);
      }
    }
    #pragma unroll
    for (int fo = 0; fo < 4; ++fo)
      #pragma unroll
      for (int i = 0; i < 4; ++i) {
        const int o = ob + fo * 16 + l4 * 4 + i;
        const float inv = gamma[o] * rsqrtf(rvar[o] + 1e-5f);
        const float addv = beta[o] - rmean[o] * inv;
        const float btv = bt[o];
        #pragma unroll
        for (int fm2 = 0; fm2 < 4; ++fm2) {
          const int m = m0 + fm2 * 16 + l15;
          float tv = t[fo][fm2][i] + btv;
          float bn = tv * inv + addv;
          float xr = x[((size_t)b * Cc + o) * Nn + m];
          out[((size_t)b * Cc + o) * Nn + m] = xr + fmaxf(bn, 0.0f);
        }
      }
  }
}

extern "C" void kernel_launch(void* const* d_in, const int* in_sizes, int n_in,
                              void* d_out, int out_size, void* d_ws, size_t ws_size,
                              hipStream_t stream) {
  const float* x = (const float*)d_in[0];
  const float* wqk = (const float*)d_in[1];
  const float* wv = (const float*)d_in[2];
  const float* bv = (const float*)d_in[3];
  const float* wt = (const float*)d_in[4];
  const float* bt = (const float*)d_in[5];
  const float* gamma = (const float*)d_in[6];
  const float* beta = (const float*)d_in[7];
  const float* rmean = (const float*)d_in[8];
  const float* rvar = (const float*)d_in[9];
  float* out = (float*)d_out;

  char* ws = (char*)d_ws;
  size_t off = 0;
  auto alloc = [&](size_t nb) {
    char* p = ws + off;
    off += (nb + 255) & ~(size_t)255;
    return p;
  };
  _Float16* qkf = (_Float16*)alloc((size_t)Bb * Nn * C4 * 2);
  _Float16* xvf = (_Float16*)alloc((size_t)Bb * Cc * Nn * 2);
  float* stats = (float*)alloc((size_t)Bb * Nn * 4);
  _Float16* wqkh = (_Float16*)alloc((size_t)C4 * Cc * 2);
  _Float16* wqkl = (_Float16*)alloc((size_t)C4 * Cc * 2);
  _Float16* wvf = (_Float16*)alloc((size_t)Cc * Cc * 2);
  _Float16* wtf = (_Float16*)alloc((size_t)Cc * Cc * 2);

  k0_weights<<<dim3(256), dim3(256), 0, stream>>>(wqk, wv, wt, wqkh, wqkl, wvf, wtf);
  k23_qkv<<<dim3(512), dim3(512), 0, stream>>>(x, wqkh, wqkl, wvf, bv, qkf, xvf);
  k4_stats<<<dim3(512), dim3(512), 0, stream>>>(qkf, stats);
  k5_main<<<dim3(512), dim3(256), 0, stream>>>(x, qkf, xvf, stats, wtf, bt,
                                               gamma, beta, rmean, rvar, out);
}